// Round 1
// 1095.342 us; speedup vs baseline: 1.2694x; 1.2694x over previous
//
#include <hip/hip_runtime.h>
#include <math.h>

// Problem constants (fixed by the harness setup)
#define NELEM 500000
#define NSAMP 16384
#define DIM   256
#define NH    8
#define HDIM  32

// ---------------- K0: segment bounds via binary search ----------------
__global__ void k0_bounds(const int* __restrict__ seg, int* __restrict__ bounds) {
    int i = blockIdx.x * blockDim.x + threadIdx.x;
    if (i > NSAMP) return;
    int lo = 0, hi = NELEM;
    while (lo < hi) {
        int mid = (lo + hi) >> 1;
        if (seg[mid] < i) lo = mid + 1; else hi = mid;
    }
    bounds[i] = lo;
}

// ---------------- K1: segment mean pooling (4 segments per 256-block, wave each) ----------------
__global__ __launch_bounds__(256) void k1_pool(const float* __restrict__ E,
                                               const int* __restrict__ bounds,
                                               float* __restrict__ pooled) {
    int l = threadIdx.x & 63;
    int s = blockIdx.x * 4 + (threadIdx.x >> 6);
    int start = bounds[s], end = bounds[s + 1];
    const float4* Ev = (const float4*)E;
    float4 a0 = make_float4(0.f, 0.f, 0.f, 0.f);
    float4 a1 = make_float4(0.f, 0.f, 0.f, 0.f);
    float4 a2 = make_float4(0.f, 0.f, 0.f, 0.f);
    float4 a3 = make_float4(0.f, 0.f, 0.f, 0.f);
    int e = start;
    for (; e + 3 < end; e += 4) {
        float4 v0 = Ev[(size_t)(e + 0) * 64 + l];
        float4 v1 = Ev[(size_t)(e + 1) * 64 + l];
        float4 v2 = Ev[(size_t)(e + 2) * 64 + l];
        float4 v3 = Ev[(size_t)(e + 3) * 64 + l];
        a0.x += v0.x; a0.y += v0.y; a0.z += v0.z; a0.w += v0.w;
        a1.x += v1.x; a1.y += v1.y; a1.z += v1.z; a1.w += v1.w;
        a2.x += v2.x; a2.y += v2.y; a2.z += v2.z; a2.w += v2.w;
        a3.x += v3.x; a3.y += v3.y; a3.z += v3.z; a3.w += v3.w;
    }
    for (; e < end; ++e) {
        float4 v0 = Ev[(size_t)e * 64 + l];
        a0.x += v0.x; a0.y += v0.y; a0.z += v0.z; a0.w += v0.w;
    }
    int cnt = end - start;
    float inv = 1.0f / (float)(cnt > 0 ? cnt : 1);
    float4 o;
    o.x = (a0.x + a1.x + a2.x + a3.x) * inv;
    o.y = (a0.y + a1.y + a2.y + a3.y) * inv;
    o.z = (a0.z + a1.z + a2.z + a3.z) * inv;
    o.w = (a0.w + a1.w + a2.w + a3.w) * inv;
    ((float4*)pooled)[(size_t)s * 64 + l] = o;
}

// ---------------- generic fp32 GEMM: C[M,256] = A[M,256] @ B[256,256] ----------------
__global__ __launch_bounds__(256) void gemm_256(const float* __restrict__ A,
                                                const float* __restrict__ B,
                                                float* __restrict__ C) {
    __shared__ float As[16][68];  // As[k][m] (transposed)
    __shared__ float Bs[16][68];  // Bs[k][n]
    int tx = threadIdx.x;
    int m0 = blockIdx.x * 64, n0 = blockIdx.y * 64;
    int ml = (tx >> 4) * 4, nl = (tx & 15) * 4;
    int lam = tx >> 2, lak = (tx & 3) * 4;
    int lbk = tx >> 4, lbn = (tx & 15) * 4;
    float acc[4][4] = {};
    for (int k0 = 0; k0 < 256; k0 += 16) {
        float4 av = *(const float4*)&A[(size_t)(m0 + lam) * 256 + k0 + lak];
        float4 bv = *(const float4*)&B[(size_t)(k0 + lbk) * 256 + n0 + lbn];
        __syncthreads();
        As[lak + 0][lam] = av.x; As[lak + 1][lam] = av.y;
        As[lak + 2][lam] = av.z; As[lak + 3][lam] = av.w;
        *(float4*)&Bs[lbk][lbn] = bv;
        __syncthreads();
#pragma unroll
        for (int k = 0; k < 16; ++k) {
            float4 a4 = *(const float4*)&As[k][ml];
            float4 b4 = *(const float4*)&Bs[k][nl];
            float aa[4] = {a4.x, a4.y, a4.z, a4.w};
            float bb[4] = {b4.x, b4.y, b4.z, b4.w};
#pragma unroll
            for (int i = 0; i < 4; ++i)
#pragma unroll
                for (int j = 0; j < 4; ++j)
                    acc[i][j] = fmaf(aa[i], bb[j], acc[i][j]);
        }
    }
#pragma unroll
    for (int i = 0; i < 4; ++i) {
        float4 o = make_float4(acc[i][0], acc[i][1], acc[i][2], acc[i][3]);
        *(float4*)&C[(size_t)(m0 + ml + i) * 256 + n0 + nl] = o;
    }
}

// ---------------- K2b: t[s,h,i] = (1/sqrt(32)) * sum_d q[s,h*32+d] * Wk[i,h*32+d] ----------------
__global__ __launch_bounds__(256) void k2b_t(const float* __restrict__ q,
                                             const float* __restrict__ Wk,
                                             float* __restrict__ t) {
    __shared__ float wkT[32][256];
    __shared__ float qT[32][64];
    int tx = threadIdx.x;
    int s0 = blockIdx.x * 64, h = blockIdx.y;
#pragma unroll
    for (int it = 0; it < 8; ++it) {
        int idx = tx + it * 256;
        int i = idx >> 3, dq = (idx & 7) * 4;
        float4 v = *(const float4*)&Wk[(size_t)i * 256 + h * 32 + dq];
        wkT[dq + 0][i] = v.x; wkT[dq + 1][i] = v.y;
        wkT[dq + 2][i] = v.z; wkT[dq + 3][i] = v.w;
    }
#pragma unroll
    for (int it = 0; it < 2; ++it) {
        int idx = tx + it * 256;
        int ss = idx >> 3, dq = (idx & 7) * 4;
        float4 v = *(const float4*)&q[(size_t)(s0 + ss) * 256 + h * 32 + dq];
        qT[dq + 0][ss] = v.x; qT[dq + 1][ss] = v.y;
        qT[dq + 2][ss] = v.z; qT[dq + 3][ss] = v.w;
    }
    __syncthreads();
    int sl = (tx >> 4) * 4, i0 = (tx & 15) * 16;
    float acc[4][16] = {};
#pragma unroll 8
    for (int k = 0; k < 32; ++k) {
        float4 q4 = *(const float4*)&qT[k][sl];
        float4 w0 = *(const float4*)&wkT[k][i0];
        float4 w1 = *(const float4*)&wkT[k][i0 + 4];
        float4 w2 = *(const float4*)&wkT[k][i0 + 8];
        float4 w3 = *(const float4*)&wkT[k][i0 + 12];
        float qa[4] = {q4.x, q4.y, q4.z, q4.w};
        float wb[16] = {w0.x, w0.y, w0.z, w0.w, w1.x, w1.y, w1.z, w1.w,
                        w2.x, w2.y, w2.z, w2.w, w3.x, w3.y, w3.z, w3.w};
#pragma unroll
        for (int a = 0; a < 4; ++a)
#pragma unroll
            for (int b = 0; b < 16; ++b)
                acc[a][b] = fmaf(qa[a], wb[b], acc[a][b]);
    }
    const float scale = 0.17677669529663687f;  // 1/sqrt(32)
#pragma unroll
    for (int a = 0; a < 4; ++a)
#pragma unroll
        for (int bq = 0; bq < 4; ++bq) {
            float4 o = make_float4(acc[a][bq * 4 + 0] * scale, acc[a][bq * 4 + 1] * scale,
                                   acc[a][bq * 4 + 2] * scale, acc[a][bq * 4 + 3] * scale);
            *(float4*)&t[(size_t)(s0 + sl + a) * 2048 + h * 256 + i0 + bq * 4] = o;
        }
}

// ---------------- K3 v2: LDS-ring async pipeline, one wave per segment ----------------
// Latency fix: 8-slot x 1KB per-wave LDS ring filled by global_load_lds (one instr stages
// a full 1KB row: uniform LDS base + lane*16B). Counted s_waitcnt vmcnt(6) keeps 7 rows
// in flight across the whole loop (never drains to 0). This takes prefetch out of the
// register allocator's hands (old version reported 76 VGPR => compiler serialized the
// register prefetch and every element paid full HBM latency).
// Bank conflicts: a 256-float row read as per-chunk ds_read_b128 puts all 8 chunk groups
// on the same banks (addrs 128B apart -> 8-way conflict). Each lane reads its 8 sub-chunks
// in rotated order idx[j] = g*8 + ((j+g)&7)  (g = lane&7) -> 8 distinct bank quads, and the
// SAME rotation is applied to the t-fragment, accumulator slots and output store, so the
// math is permutation-invariant.
// Softmax: defer-max (threshold 20). Scores have sigma ~0.2 by construction, so the rescale
// branch is effectively never taken; per element this saves one __expf and 32 rescale FMAs
// (acc update is a pure fma(p, r, acc)). Exact-safe for any input: m only goes stale by <=20,
// p <= e^20, d <= n*e^20 (no overflow), and p >= e^-20 at the true max (no全 underflow).
__device__ __forceinline__ void stage_row(const float* __restrict__ E, int e,
                                          float* lds_base, int l) {
    const float* g = E + (size_t)e * 256 + l * 4;  // lane l supplies bytes [16l, 16l+16)
    __builtin_amdgcn_global_load_lds(
        (const __attribute__((address_space(1))) void*)g,
        (__attribute__((address_space(3))) void*)lds_base, 16, 0, 0);
}

__global__ __launch_bounds__(256) void k3_flash(const float* __restrict__ E,
                                                const float* __restrict__ t,
                                                const int* __restrict__ bounds,
                                                float* __restrict__ pw) {
    __shared__ float rows[4][8][256];  // 4 waves x 8-slot ring x 1KB row = 32KB
    int l = threadIdx.x & 63;
    int w = threadIdx.x >> 6;
    int s = blockIdx.x * 4 + w;
    int start = bounds[s], end = bounds[s + 1];
    int g = l & 7, h = l >> 3;

    float* o_row = pw + (size_t)s * 2048 + h * 256;  // lane's float4s live at idx[j]
    if (start >= end) {
        float4 z = make_float4(0.f, 0.f, 0.f, 0.f);
#pragma unroll
        for (int j = 0; j < 8; ++j) ((float4*)o_row)[g * 8 + j] = z;
        return;
    }

    // rotated float4 indices within the lane's own 32-float chunk
    int idx[8];
#pragma unroll
    for (int j = 0; j < 8; ++j) idx[j] = g * 8 + ((j + g) & 7);

    // t fragment (rotated to match)
    const float4* t_row = (const float4*)(t + (size_t)s * 2048 + h * 256);
    float4 tv[8];
#pragma unroll
    for (int j = 0; j < 8; ++j) tv[j] = t_row[idx[j]];

    // prologue: stage up to 7 rows into the ring
    int lim = (end - start < 7) ? end : start + 7;
    for (int e = start; e < lim; ++e)
        stage_row(E, e, &rows[w][e & 7][0], l);

    float m = 0.f, d = 0.f;
    float4 acc[8];
#pragma unroll
    for (int j = 0; j < 8; ++j) acc[j] = make_float4(0.f, 0.f, 0.f, 0.f);

    auto consume = [&](int slot) {
        const float4* rp = (const float4*)&rows[w][slot][0];
        float4 r[8];
#pragma unroll
        for (int j = 0; j < 8; ++j) r[j] = rp[idx[j]];  // conflict-free via rotation
        float q0 = 0.f, q1 = 0.f, q2 = 0.f, q3 = 0.f;
#pragma unroll
        for (int j = 0; j < 8; j += 4) {
            q0 = fmaf(r[j].x, tv[j].x, q0);
            q0 = fmaf(r[j].y, tv[j].y, q0);
            q0 = fmaf(r[j].z, tv[j].z, q0);
            q0 = fmaf(r[j].w, tv[j].w, q0);
            q1 = fmaf(r[j + 1].x, tv[j + 1].x, q1);
            q1 = fmaf(r[j + 1].y, tv[j + 1].y, q1);
            q1 = fmaf(r[j + 1].z, tv[j + 1].z, q1);
            q1 = fmaf(r[j + 1].w, tv[j + 1].w, q1);
            q2 = fmaf(r[j + 2].x, tv[j + 2].x, q2);
            q2 = fmaf(r[j + 2].y, tv[j + 2].y, q2);
            q2 = fmaf(r[j + 2].z, tv[j + 2].z, q2);
            q2 = fmaf(r[j + 2].w, tv[j + 2].w, q2);
            q3 = fmaf(r[j + 3].x, tv[j + 3].x, q3);
            q3 = fmaf(r[j + 3].y, tv[j + 3].y, q3);
            q3 = fmaf(r[j + 3].z, tv[j + 3].z, q3);
            q3 = fmaf(r[j + 3].w, tv[j + 3].w, q3);
        }
        float sc = (q0 + q1) + (q2 + q3);
        sc += __shfl_xor(sc, 1, 64);
        sc += __shfl_xor(sc, 2, 64);
        sc += __shfl_xor(sc, 4, 64);
        if (sc - m > 20.f) {  // defer-max rescale: effectively never taken
            float rs = __expf(m - sc);
            d *= rs;
#pragma unroll
            for (int j = 0; j < 8; ++j) {
                acc[j].x *= rs; acc[j].y *= rs; acc[j].z *= rs; acc[j].w *= rs;
            }
            m = sc;
        }
        float p = __expf(sc - m);
        d += p;
#pragma unroll
        for (int j = 0; j < 8; ++j) {
            acc[j].x = fmaf(p, r[j].x, acc[j].x);
            acc[j].y = fmaf(p, r[j].y, acc[j].y);
            acc[j].z = fmaf(p, r[j].z, acc[j].z);
            acc[j].w = fmaf(p, r[j].w, acc[j].w);
        }
    };

    int e = start;
    for (; e + 7 < end; ++e) {
        // row e is ready once <=6 of the 7 in-flight rows remain outstanding
        asm volatile("s_waitcnt vmcnt(6)" ::: "memory");
        consume(e & 7);
        // refill the slot read 1 iteration ago ((e+7)&7 != e&7) -> safe overwrite margin
        stage_row(E, e + 7, &rows[w][(e + 7) & 7][0], l);
    }
    asm volatile("s_waitcnt vmcnt(0)" ::: "memory");
    for (; e < end; ++e) consume(e & 7);

    float rd = 1.0f / d;
#pragma unroll
    for (int j = 0; j < 8; ++j) {
        float4 v = make_float4(acc[j].x * rd, acc[j].y * rd, acc[j].z * rd, acc[j].w * rd);
        ((float4*)o_row)[idx[j]] = v;
    }
}

// ---------------- K4a: ps[s,h*32+d] = sum_k pw[s,h,k] * Wv[k,h*32+d] ----------------
__global__ __launch_bounds__(256) void k4a_ps(const float* __restrict__ pw,
                                              const float* __restrict__ Wv,
                                              float* __restrict__ ps) {
    __shared__ float at[32][68];
    __shared__ float bt[32][36];
    int tx = threadIdx.x;
    int s0 = blockIdx.x * 64, h = blockIdx.y;
    int dd = tx & 31, sl = (tx >> 5) * 8;
    float acc[8] = {};
    for (int k0 = 0; k0 < 256; k0 += 32) {
        __syncthreads();
#pragma unroll
        for (int it = 0; it < 2; ++it) {
            int idx = tx + it * 256;
            int ss = idx >> 3, kq = (idx & 7) * 4;
            float4 v = *(const float4*)&pw[(size_t)(s0 + ss) * 2048 + h * 256 + k0 + kq];
            at[kq + 0][ss] = v.x; at[kq + 1][ss] = v.y;
            at[kq + 2][ss] = v.z; at[kq + 3][ss] = v.w;
        }
        {
            int k = tx >> 3, dq = (tx & 7) * 4;
            float4 v = *(const float4*)&Wv[(size_t)(k0 + k) * 256 + h * 32 + dq];
            *(float4*)&bt[k][dq] = v;
        }
        __syncthreads();
#pragma unroll
        for (int k = 0; k < 32; ++k) {
            float b = bt[k][dd];
            float4 a0 = *(const float4*)&at[k][sl];
            float4 a1 = *(const float4*)&at[k][sl + 4];
            acc[0] = fmaf(a0.x, b, acc[0]); acc[1] = fmaf(a0.y, b, acc[1]);
            acc[2] = fmaf(a0.z, b, acc[2]); acc[3] = fmaf(a0.w, b, acc[3]);
            acc[4] = fmaf(a1.x, b, acc[4]); acc[5] = fmaf(a1.y, b, acc[5]);
            acc[6] = fmaf(a1.z, b, acc[6]); acc[7] = fmaf(a1.w, b, acc[7]);
        }
    }
#pragma unroll
    for (int j = 0; j < 8; ++j)
        ps[(size_t)(s0 + sl + j) * 256 + h * 32 + dd] = acc[j];
}

// ---------------- launch ----------------
// Workspace layout (floats):
//   pooled/ps : 0          (4,194,304)   -- ps reuses pooled (dead after gemm q)
//   q         : 4,194,304  (4,194,304)
//   t         : 8,388,608  (33,554,432)
//   pw        : 41,943,040 (33,554,432)  -- cannot alias t (k3 reads t while writing pw)
//   bounds    : 75,497,472 (16,385 ints)
// Total ~302 MB (same as R0 layout, known to fit).
extern "C" void kernel_launch(void* const* d_in, const int* in_sizes, int n_in,
                              void* d_out, int out_size, void* d_ws, size_t ws_size,
                              hipStream_t stream) {
    const float* E  = (const float*)d_in[0];
    const int* seg  = (const int*)d_in[1];
    const float* Wq = (const float*)d_in[3];
    const float* Wk = (const float*)d_in[4];
    const float* Wv = (const float*)d_in[5];
    const float* Wo = (const float*)d_in[6];
    float* out = (float*)d_out;
    float* ws = (float*)d_ws;

    float* pooled = ws;
    float* q      = ws + 4194304;
    float* t      = ws + 8388608;
    float* pw     = ws + 41943040;
    int* bounds   = (int*)(ws + 75497472);
    float* ps     = pooled;

    k0_bounds<<<(NSAMP + 256) / 256, 256, 0, stream>>>(seg, bounds);
    k1_pool<<<NSAMP / 4, 256, 0, stream>>>(E, bounds, pooled);
    gemm_256<<<dim3(NSAMP / 64, 4), 256, 0, stream>>>(pooled, Wq, q);
    k2b_t<<<dim3(NSAMP / 64, NH), 256, 0, stream>>>(q, Wk, t);
    k3_flash<<<NSAMP / 4, 256, 0, stream>>>(E, t, bounds, pw);
    k4a_ps<<<dim3(NSAMP / 64, NH), 256, 0, stream>>>(pw, Wv, ps);
    gemm_256<<<dim3(NSAMP / 64, 4), 256, 0, stream>>>(ps, Wo, out);
}

// Round 2
// 1059.216 us; speedup vs baseline: 1.3127x; 1.0341x over previous
//
#include <hip/hip_runtime.h>
#include <math.h>

// Problem constants (fixed by the harness setup)
#define NELEM 500000
#define NSAMP 16384
#define DIM   256
#define NH    8
#define HDIM  32

// ---------------- K0: segment bounds via binary search ----------------
__global__ void k0_bounds(const int* __restrict__ seg, int* __restrict__ bounds) {
    int i = blockIdx.x * blockDim.x + threadIdx.x;
    if (i > NSAMP) return;
    int lo = 0, hi = NELEM;
    while (lo < hi) {
        int mid = (lo + hi) >> 1;
        if (seg[mid] < i) lo = mid + 1; else hi = mid;
    }
    bounds[i] = lo;
}

// ---------------- shared staging helper: one instr stages a full 1KB row ----------------
// LDS dest is wave-uniform base + lane*16B (HW rule); global src is per-lane.
__device__ __forceinline__ void stage_row(const float* __restrict__ E, int e,
                                          float* lds_base, int l) {
    const float* g = E + (size_t)e * 256 + l * 4;  // lane l supplies bytes [16l, 16l+16)
    __builtin_amdgcn_global_load_lds(
        (const __attribute__((address_space(1))) void*)g,
        (__attribute__((address_space(3))) void*)lds_base, 16, 0, 0);
}

// ---------------- K1 v2: segment mean pooling, 2 waves per segment + LDS ring ----------------
// Same proven pipeline as k3: 8-slot x 1KB ring per wave, counted vmcnt(6) keeps 7 rows in
// flight (the R0->R1 fix showed register prefetch gets serialized by the compiler; the ring
// does not). Segment split across a wave pair halves the serial chain and doubles wave-level
// parallelism; merge is a single LDS add (wave1 dumps its partial into its own drained ring).
__global__ __launch_bounds__(256) void k1_pool(const float* __restrict__ E,
                                               const int* __restrict__ bounds,
                                               float* __restrict__ pooled) {
    __shared__ float rows[4][8][256];  // 4 waves x 8-slot ring = 32 KB
    int l = threadIdx.x & 63;
    int w = threadIdx.x >> 6;
    int pair = w >> 1, half = w & 1;
    int s = blockIdx.x * 2 + pair;
    int start = bounds[s], end = bounds[s + 1];
    int n = end - start;
    int nA = (n + 1) >> 1;
    int b0 = start + (half ? nA : 0);
    int b1 = half ? end : start + nA;

    int lim = (b1 - b0 < 7) ? b1 : b0 + 7;
    for (int e = b0; e < lim; ++e) stage_row(E, e, &rows[w][(e - b0) & 7][0], l);

    float4 acc = make_float4(0.f, 0.f, 0.f, 0.f);
    int e = b0;
    for (; e + 7 < b1; ++e) {
        asm volatile("s_waitcnt vmcnt(6)" ::: "memory");
        float4 v = *(const float4*)&rows[w][(e - b0) & 7][l * 4];
        acc.x += v.x; acc.y += v.y; acc.z += v.z; acc.w += v.w;
        stage_row(E, e + 7, &rows[w][(e + 7 - b0) & 7][0], l);
    }
    asm volatile("s_waitcnt vmcnt(0)" ::: "memory");
    for (; e < b1; ++e) {
        float4 v = *(const float4*)&rows[w][(e - b0) & 7][l * 4];
        acc.x += v.x; acc.y += v.y; acc.z += v.z; acc.w += v.w;
    }
    // merge: wave1 dumps partial into its own (drained) ring slot 0; wave0 combines
    if (half == 1) *(float4*)&rows[w][0][l * 4] = acc;
    __syncthreads();
    if (half == 0) {
        float4 p = *(const float4*)&rows[w + 1][0][l * 4];
        float inv = 1.0f / (float)(n > 0 ? n : 1);
        float4 o;
        o.x = (acc.x + p.x) * inv;
        o.y = (acc.y + p.y) * inv;
        o.z = (acc.z + p.z) * inv;
        o.w = (acc.w + p.w) * inv;
        *(float4*)&pooled[(size_t)s * 256 + l * 4] = o;
    }
}

// ---------------- generic fp32 GEMM: C[M,256] = A[M,256] @ B[256,256] ----------------
__global__ __launch_bounds__(256) void gemm_256(const float* __restrict__ A,
                                                const float* __restrict__ B,
                                                float* __restrict__ C) {
    __shared__ float As[16][68];  // As[k][m] (transposed)
    __shared__ float Bs[16][68];  // Bs[k][n]
    int tx = threadIdx.x;
    int m0 = blockIdx.x * 64, n0 = blockIdx.y * 64;
    int ml = (tx >> 4) * 4, nl = (tx & 15) * 4;
    int lam = tx >> 2, lak = (tx & 3) * 4;
    int lbk = tx >> 4, lbn = (tx & 15) * 4;
    float acc[4][4] = {};
    for (int k0 = 0; k0 < 256; k0 += 16) {
        float4 av = *(const float4*)&A[(size_t)(m0 + lam) * 256 + k0 + lak];
        float4 bv = *(const float4*)&B[(size_t)(k0 + lbk) * 256 + n0 + lbn];
        __syncthreads();
        As[lak + 0][lam] = av.x; As[lak + 1][lam] = av.y;
        As[lak + 2][lam] = av.z; As[lak + 3][lam] = av.w;
        *(float4*)&Bs[lbk][lbn] = bv;
        __syncthreads();
#pragma unroll
        for (int k = 0; k < 16; ++k) {
            float4 a4 = *(const float4*)&As[k][ml];
            float4 b4 = *(const float4*)&Bs[k][nl];
            float aa[4] = {a4.x, a4.y, a4.z, a4.w};
            float bb[4] = {b4.x, b4.y, b4.z, b4.w};
#pragma unroll
            for (int i = 0; i < 4; ++i)
#pragma unroll
                for (int j = 0; j < 4; ++j)
                    acc[i][j] = fmaf(aa[i], bb[j], acc[i][j]);
        }
    }
#pragma unroll
    for (int i = 0; i < 4; ++i) {
        float4 o = make_float4(acc[i][0], acc[i][1], acc[i][2], acc[i][3]);
        *(float4*)&C[(size_t)(m0 + ml + i) * 256 + n0 + nl] = o;
    }
}

// ---------------- K2b: t[s,h,i] = (1/sqrt(32)) * sum_d q[s,h*32+d] * Wk[i,h*32+d] ----------------
__global__ __launch_bounds__(256) void k2b_t(const float* __restrict__ q,
                                             const float* __restrict__ Wk,
                                             float* __restrict__ t) {
    __shared__ float wkT[32][256];
    __shared__ float qT[32][64];
    int tx = threadIdx.x;
    int s0 = blockIdx.x * 64, h = blockIdx.y;
#pragma unroll
    for (int it = 0; it < 8; ++it) {
        int idx = tx + it * 256;
        int i = idx >> 3, dq = (idx & 7) * 4;
        float4 v = *(const float4*)&Wk[(size_t)i * 256 + h * 32 + dq];
        wkT[dq + 0][i] = v.x; wkT[dq + 1][i] = v.y;
        wkT[dq + 2][i] = v.z; wkT[dq + 3][i] = v.w;
    }
#pragma unroll
    for (int it = 0; it < 2; ++it) {
        int idx = tx + it * 256;
        int ss = idx >> 3, dq = (idx & 7) * 4;
        float4 v = *(const float4*)&q[(size_t)(s0 + ss) * 256 + h * 32 + dq];
        qT[dq + 0][ss] = v.x; qT[dq + 1][ss] = v.y;
        qT[dq + 2][ss] = v.z; qT[dq + 3][ss] = v.w;
    }
    __syncthreads();
    int sl = (tx >> 4) * 4, i0 = (tx & 15) * 16;
    float acc[4][16] = {};
#pragma unroll 8
    for (int k = 0; k < 32; ++k) {
        float4 q4 = *(const float4*)&qT[k][sl];
        float4 w0 = *(const float4*)&wkT[k][i0];
        float4 w1 = *(const float4*)&wkT[k][i0 + 4];
        float4 w2 = *(const float4*)&wkT[k][i0 + 8];
        float4 w3 = *(const float4*)&wkT[k][i0 + 12];
        float qa[4] = {q4.x, q4.y, q4.z, q4.w};
        float wb[16] = {w0.x, w0.y, w0.z, w0.w, w1.x, w1.y, w1.z, w1.w,
                        w2.x, w2.y, w2.z, w2.w, w3.x, w3.y, w3.z, w3.w};
#pragma unroll
        for (int a = 0; a < 4; ++a)
#pragma unroll
            for (int b = 0; b < 16; ++b)
                acc[a][b] = fmaf(qa[a], wb[b], acc[a][b]);
    }
    const float scale = 0.17677669529663687f;  // 1/sqrt(32)
#pragma unroll
    for (int a = 0; a < 4; ++a)
#pragma unroll
        for (int bq = 0; bq < 4; ++bq) {
            float4 o = make_float4(acc[a][bq * 4 + 0] * scale, acc[a][bq * 4 + 1] * scale,
                                   acc[a][bq * 4 + 2] * scale, acc[a][bq * 4 + 3] * scale);
            *(float4*)&t[(size_t)(s0 + sl + a) * 2048 + h * 256 + i0 + bq * 4] = o;
        }
}

// ---------------- K3 v3: LDS-ring async pipeline, TWO waves per segment ----------------
// R1's ring fixed the load latency; remaining cost is the ~400cy/element dependent chain
// (ds_read -> dot -> 3 dependent shuffles -> exp -> acc) x ~30.5 elements per wave. Split
// each segment across a wave pair: halves the serial chain, doubles wave parallelism
// (32768 waves), halves tail imbalance. Online-softmax states merge exactly:
//   m* = max(m0,m1); out = (a0*acc0 + a1*acc1) / (a0*d0 + a1*d1),  ai = exp(mi - m*).
// This is scale-invariant, so an empty half (m=0,d=0,acc=0) merges correctly for free.
// Wave1 dumps its acc (8KB) into its OWN drained ring (no extra LDS); per-head (m,d) go in
// a 128B side array. Rotation idx[j] = g*8 + ((j+g)&7) keeps all LDS reads conflict-free.
__global__ __launch_bounds__(256) void k3_flash(const float* __restrict__ E,
                                                const float* __restrict__ t,
                                                const int* __restrict__ bounds,
                                                float* __restrict__ pw) {
    __shared__ float rows[4][8][256];  // 4 waves x 8-slot ring x 1KB row = 32KB
    __shared__ float md[2][2][8];      // [pair][{m,d}][head] of wave1
    int l = threadIdx.x & 63;
    int w = threadIdx.x >> 6;
    int pair = w >> 1, half = w & 1;
    int s = blockIdx.x * 2 + pair;
    int start = bounds[s], end = bounds[s + 1];
    int n = end - start;
    int g = l & 7, h = l >> 3;
    int nA = (n + 1) >> 1;
    int b0 = start + (half ? nA : 0);
    int b1 = half ? end : start + nA;

    // rotated float4 indices within the lane's own 32-float chunk (bank-conflict-free)
    int idx[8];
#pragma unroll
    for (int j = 0; j < 8; ++j) idx[j] = g * 8 + ((j + g) & 7);

    // t fragment (rotated to match)
    const float4* t_row = (const float4*)(t + (size_t)s * 2048 + h * 256);
    float4 tv[8];
#pragma unroll
    for (int j = 0; j < 8; ++j) tv[j] = t_row[idx[j]];

    // prologue: stage up to 7 rows of this wave's half into the ring
    int lim = (b1 - b0 < 7) ? b1 : b0 + 7;
    for (int e = b0; e < lim; ++e) stage_row(E, e, &rows[w][(e - b0) & 7][0], l);

    float m = 0.f, d = 0.f;
    float4 acc[8];
#pragma unroll
    for (int j = 0; j < 8; ++j) acc[j] = make_float4(0.f, 0.f, 0.f, 0.f);

    auto consume = [&](int slot) {
        const float4* rp = (const float4*)&rows[w][slot][0];
        float4 r[8];
#pragma unroll
        for (int j = 0; j < 8; ++j) r[j] = rp[idx[j]];  // conflict-free via rotation
        float q0 = 0.f, q1 = 0.f, q2 = 0.f, q3 = 0.f;
#pragma unroll
        for (int j = 0; j < 8; j += 4) {
            q0 = fmaf(r[j].x, tv[j].x, q0);
            q0 = fmaf(r[j].y, tv[j].y, q0);
            q0 = fmaf(r[j].z, tv[j].z, q0);
            q0 = fmaf(r[j].w, tv[j].w, q0);
            q1 = fmaf(r[j + 1].x, tv[j + 1].x, q1);
            q1 = fmaf(r[j + 1].y, tv[j + 1].y, q1);
            q1 = fmaf(r[j + 1].z, tv[j + 1].z, q1);
            q1 = fmaf(r[j + 1].w, tv[j + 1].w, q1);
            q2 = fmaf(r[j + 2].x, tv[j + 2].x, q2);
            q2 = fmaf(r[j + 2].y, tv[j + 2].y, q2);
            q2 = fmaf(r[j + 2].z, tv[j + 2].z, q2);
            q2 = fmaf(r[j + 2].w, tv[j + 2].w, q2);
            q3 = fmaf(r[j + 3].x, tv[j + 3].x, q3);
            q3 = fmaf(r[j + 3].y, tv[j + 3].y, q3);
            q3 = fmaf(r[j + 3].z, tv[j + 3].z, q3);
            q3 = fmaf(r[j + 3].w, tv[j + 3].w, q3);
        }
        float sc = (q0 + q1) + (q2 + q3);
        sc += __shfl_xor(sc, 1, 64);
        sc += __shfl_xor(sc, 2, 64);
        sc += __shfl_xor(sc, 4, 64);
        if (sc - m > 20.f) {  // defer-max rescale: effectively never taken
            float rs = __expf(m - sc);
            d *= rs;
#pragma unroll
            for (int j = 0; j < 8; ++j) {
                acc[j].x *= rs; acc[j].y *= rs; acc[j].z *= rs; acc[j].w *= rs;
            }
            m = sc;
        }
        float p = __expf(sc - m);
        d += p;
#pragma unroll
        for (int j = 0; j < 8; ++j) {
            acc[j].x = fmaf(p, r[j].x, acc[j].x);
            acc[j].y = fmaf(p, r[j].y, acc[j].y);
            acc[j].z = fmaf(p, r[j].z, acc[j].z);
            acc[j].w = fmaf(p, r[j].w, acc[j].w);
        }
    };

    int e = b0;
    for (; e + 7 < b1; ++e) {
        asm volatile("s_waitcnt vmcnt(6)" ::: "memory");
        consume((e - b0) & 7);
        stage_row(E, e + 7, &rows[w][(e + 7 - b0) & 7][0], l);
    }
    asm volatile("s_waitcnt vmcnt(0)" ::: "memory");
    for (; e < b1; ++e) consume((e - b0) & 7);

    // ---- merge across the wave pair ----
    if (half == 1) {
        float4* dump = (float4*)&rows[w][0][0];  // own ring is drained; 8KB = exactly acc
#pragma unroll
        for (int j = 0; j < 8; ++j) dump[j * 64 + l] = acc[j];  // lane-stride-16B: free
        if (g == 0) { md[pair][0][h] = m; md[pair][1][h] = d; }
    }
    __syncthreads();
    if (half == 0) {
        float* o_row = pw + (size_t)s * 2048 + h * 256;
        if (n == 0) {
            float4 z = make_float4(0.f, 0.f, 0.f, 0.f);
#pragma unroll
            for (int j = 0; j < 8; ++j) ((float4*)o_row)[j] = z;
        } else {
            float m1 = md[pair][0][h], d1 = md[pair][1][h];
            float mstar = fmaxf(m, m1);
            float a0 = __expf(m - mstar), a1 = __expf(m1 - mstar);
            float rd = 1.0f / (a0 * d + a1 * d1);
            const float4* dump = (const float4*)&rows[w + 1][0][0];
#pragma unroll
            for (int j = 0; j < 8; ++j) {
                float4 p = dump[j * 64 + l];
                float4 v;
                v.x = (a0 * acc[j].x + a1 * p.x) * rd;
                v.y = (a0 * acc[j].y + a1 * p.y) * rd;
                v.z = (a0 * acc[j].z + a1 * p.z) * rd;
                v.w = (a0 * acc[j].w + a1 * p.w) * rd;
                ((float4*)o_row)[idx[j]] = v;
            }
        }
    }
}

// ---------------- K4a: ps[s,h*32+d] = sum_k pw[s,h,k] * Wv[k,h*32+d] ----------------
__global__ __launch_bounds__(256) void k4a_ps(const float* __restrict__ pw,
                                              const float* __restrict__ Wv,
                                              float* __restrict__ ps) {
    __shared__ float at[32][68];
    __shared__ float bt[32][36];
    int tx = threadIdx.x;
    int s0 = blockIdx.x * 64, h = blockIdx.y;
    int dd = tx & 31, sl = (tx >> 5) * 8;
    float acc[8] = {};
    for (int k0 = 0; k0 < 256; k0 += 32) {
        __syncthreads();
#pragma unroll
        for (int it = 0; it < 2; ++it) {
            int idx = tx + it * 256;
            int ss = idx >> 3, kq = (idx & 7) * 4;
            float4 v = *(const float4*)&pw[(size_t)(s0 + ss) * 2048 + h * 256 + k0 + kq];
            at[kq + 0][ss] = v.x; at[kq + 1][ss] = v.y;
            at[kq + 2][ss] = v.z; at[kq + 3][ss] = v.w;
        }
        {
            int k = tx >> 3, dq = (tx & 7) * 4;
            float4 v = *(const float4*)&Wv[(size_t)(k0 + k) * 256 + h * 32 + dq];
            *(float4*)&bt[k][dq] = v;
        }
        __syncthreads();
#pragma unroll
        for (int k = 0; k < 32; ++k) {
            float b = bt[k][dd];
            float4 a0 = *(const float4*)&at[k][sl];
            float4 a1 = *(const float4*)&at[k][sl + 4];
            acc[0] = fmaf(a0.x, b, acc[0]); acc[1] = fmaf(a0.y, b, acc[1]);
            acc[2] = fmaf(a0.z, b, acc[2]); acc[3] = fmaf(a0.w, b, acc[3]);
            acc[4] = fmaf(a1.x, b, acc[4]); acc[5] = fmaf(a1.y, b, acc[5]);
            acc[6] = fmaf(a1.z, b, acc[6]); acc[7] = fmaf(a1.w, b, acc[7]);
        }
    }
#pragma unroll
    for (int j = 0; j < 8; ++j)
        ps[(size_t)(s0 + sl + j) * 256 + h * 32 + dd] = acc[j];
}

// ---------------- launch ----------------
// Workspace layout (floats):
//   pooled/ps : 0          (4,194,304)   -- ps reuses pooled (dead after gemm q)
//   q         : 4,194,304  (4,194,304)
//   t         : 8,388,608  (33,554,432)
//   pw        : 41,943,040 (33,554,432)  -- cannot alias t (k3 reads t while writing pw)
//   bounds    : 75,497,472 (16,385 ints)
extern "C" void kernel_launch(void* const* d_in, const int* in_sizes, int n_in,
                              void* d_out, int out_size, void* d_ws, size_t ws_size,
                              hipStream_t stream) {
    const float* E  = (const float*)d_in[0];
    const int* seg  = (const int*)d_in[1];
    const float* Wq = (const float*)d_in[3];
    const float* Wk = (const float*)d_in[4];
    const float* Wv = (const float*)d_in[5];
    const float* Wo = (const float*)d_in[6];
    float* out = (float*)d_out;
    float* ws = (float*)d_ws;

    float* pooled = ws;
    float* q      = ws + 4194304;
    float* t      = ws + 8388608;
    float* pw     = ws + 41943040;
    int* bounds   = (int*)(ws + 75497472);
    float* ps     = pooled;

    k0_bounds<<<(NSAMP + 256) / 256, 256, 0, stream>>>(seg, bounds);
    k1_pool<<<NSAMP / 2, 256, 0, stream>>>(E, bounds, pooled);
    gemm_256<<<dim3(NSAMP / 64, 4), 256, 0, stream>>>(pooled, Wq, q);
    k2b_t<<<dim3(NSAMP / 64, NH), 256, 0, stream>>>(q, Wk, t);
    k3_flash<<<NSAMP / 2, 256, 0, stream>>>(E, t, bounds, pw);
    k4a_ps<<<dim3(NSAMP / 64, NH), 256, 0, stream>>>(pw, Wv, ps);
    gemm_256<<<dim3(NSAMP / 64, 4), 256, 0, stream>>>(ps, Wo, out);
}